// Round 9
// baseline (139.509 us; speedup 1.0000x reference)
//
#include <hip/hip_runtime.h>
#include <hip/hip_bf16.h>
#include <math.h>

#define B 8
#define N 2048
#define C 16
#define HID 128
#define NRF 16384      // 128*128
#define MAXLEN 8
#define MAXCH 2048     // max chains per batch (<= N)

__device__ __forceinline__ float sigf(float x) { return 1.f / (1.f + expf(-x)); }

// ---------------- pre: per-batch build (LDS counters) + weight transpose ---
// Blocks 0..7: one batch each, 1024 threads, cntrf in LDS (64 KB) -> no
// global init dependency, no cross-block atomics (R0/R1 lesson structural).
// Blocks 8..80: weight transpose + bias (independent, same dispatch).
__global__ __launch_bounds__(1024) void k_pre(
    const int* __restrict__ coords, const float* __restrict__ w_ih,
    const float* __restrict__ w_hh, const float* __restrict__ b_ih,
    const float* __restrict__ b_hh, float* __restrict__ w_ih_T,
    float* __restrict__ w_hh_T, float* __restrict__ biassum,
    int* __restrict__ map, int* __restrict__ cnt, int* __restrict__ chainrf,
    int* __restrict__ chainlen, int* __restrict__ slots) {
    int tid = threadIdx.x;
    if (blockIdx.x < 8) {
        int bb = blockIdx.x;
        __shared__ int cnt_l[NRF];          // 64 KB
        __shared__ int nch_l;
#pragma unroll
        for (int i = 0; i < 16; i++) cnt_l[tid + 1024 * i] = 0;
        if (tid == 0) nch_l = 0;
#pragma unroll
        for (int i = 0; i < 16; i++) map[bb * NRF + tid + 1024 * i] = -1;
        __syncthreads();
        int n0 = tid, n1 = tid + 1024;
        int2 c0 = ((const int2*)coords)[bb * N + n0];
        int2 c1 = ((const int2*)coords)[bb * N + n1];
        int rf0 = c0.y * 128 + c0.x;
        int rf1 = c1.y * 128 + c1.x;
        int pos0 = atomicAdd(&cnt_l[rf0], 1);
        int pos1 = atomicAdd(&cnt_l[rf1], 1);
        if (pos0 < MAXLEN) slots[((size_t)bb * NRF + rf0) * MAXLEN + pos0] = n0;
        if (pos1 < MAXLEN) slots[((size_t)bb * NRF + rf1) * MAXLEN + pos1] = n1;
        __syncthreads();                    // counts final
#pragma unroll
        for (int e = 0; e < 2; e++) {
            int rf = e ? rf1 : rf0;
            int pos = e ? pos1 : pos0;
            if (pos == 0) {                 // chain head registers chain
                int j = atomicAdd(&nch_l, 1);            // LDS atomic
                int len = cnt_l[rf];
                if (len > MAXLEN) len = MAXLEN;
                chainrf[bb * MAXCH + j] = rf;
                chainlen[bb * MAXCH + j] = len;
                map[bb * NRF + rf] = j;
            }
        }
        __syncthreads();
        if (tid == 0) cnt[bb] = nch_l;
    } else {
        int i = (blockIdx.x - 8) * 1024 + tid;   // 73 blocks cover 74240
        if (i < C * 512) {                 // w_ih_T[c][j] = w_ih[j][c]
            int c = i >> 9, j = i & 511;
            w_ih_T[i] = w_ih[j * C + c];
        }
        if (i < HID * 512) {               // w_hh_T[k][j] = w_hh[j][k]
            int k = i >> 9, j = i & 511;
            w_hh_T[i] = w_hh[j * HID + k];
        }
        if (i < 512) biassum[i] = b_ih[i] + b_hh[i];
    }
}

// ---------------- phase: step-0 for EVERY chain + in-block recurrence ------
// R8 fusion: a block's multi chains have their step-0 state computed in this
// very block -> no cross-block dep -> recurrence fused here (k_recur dispatch
// deleted; cfin deleted). 2048 blocks, 8 slots/block, 2 chains/wave for the
// step-0 pass; block-wide (2 gate cols/thread) for its ~0.46 avg multi slots.
__global__ __launch_bounds__(256) void k_phase(
    const float* __restrict__ features, const float* __restrict__ w_ih_T,
    const float* __restrict__ w_hh_T, const float* __restrict__ biassum,
    const int* __restrict__ cnt, const int* __restrict__ chainrf,
    const int* __restrict__ chainlen, int* __restrict__ slots,
    float* __restrict__ hfin) {
    int tid = threadIdx.x;
    int bb = blockIdx.x >> 8;              // 256 blocks per batch
    int slot0 = (blockIdx.x & 255) * 8;
    __shared__ float ls_w[C * 512];        // 32 KB
    __shared__ float ls_b[512];
    __shared__ float h_st[8][HID], c_st[8][HID];   // multi-chain state, 8 KB
    __shared__ float g_s[512];
    __shared__ float x_s[16];
    __shared__ int l_idx[8], l_len[8], l_ev0[8];
    int nc = cnt[bb];
    if (tid < 8) {
        int j = slot0 + tid;
        int idx = bb * MAXCH + j;
        if (j < nc) {
            int len = chainlen[idx];
            int* sl = slots + ((size_t)bb * NRF + chainrf[idx]) * MAXLEN;
            int ev0;
            if (len >= 2) {                // time-sort slots, write back
                int ev[MAXLEN];
#pragma unroll
                for (int t = 0; t < MAXLEN; t++) {
                    int v = sl[t];
                    ev[t] = (t < len) ? v : 0x7fffffff;
                }
#pragma unroll
                for (int a = 0; a < MAXLEN; a++)
#pragma unroll
                    for (int q = 0; q < MAXLEN - 1; q++) {
                        int u = ev[q], v = ev[q + 1];
                        ev[q] = min(u, v);
                        ev[q + 1] = max(u, v);
                    }
                for (int t = 0; t < len; t++) sl[t] = ev[t];
                ev0 = ev[0];
            } else {
                ev0 = sl[0];
            }
            l_idx[tid] = idx; l_len[tid] = len; l_ev0[tid] = ev0;
        } else {
            l_idx[tid] = -1; l_len[tid] = 0;
        }
    }
    for (int i = tid; i < C * 128; i += 256)        // float4 staging (8 iters)
        ((float4*)ls_w)[i] = ((const float4*)w_ih_T)[i];
    ls_b[tid] = biassum[tid];
    ls_b[tid + 256] = biassum[tid + 256];
    __syncthreads();
    int w = tid >> 6, lane = tid & 63;
    // ---- step-0 for this block's 8 slots (c_prev=0 -> f-gate dead) ----
#pragma unroll
    for (int s2 = 0; s2 < 2; s2++) {
        int s = 2 * w + s2;
        int idx = l_idx[s];
        if (idx < 0) continue;
        int len = l_len[s];
        int n = l_ev0[s];
        float f = 0.f;
        if (lane < 16) f = features[((size_t)(bb * N + n)) * C + lane];
        float ai0 = ls_b[lane],       ai1 = ls_b[lane + 64];
        float ag0 = ls_b[lane + 256], ag1 = ls_b[lane + 320];
        float ao0 = ls_b[lane + 384], ao1 = ls_b[lane + 448];
#pragma unroll
        for (int c2 = 0; c2 < 16; c2++) {
            float xv = __shfl(f, c2, 64);
            ai0 += ls_w[c2 * 512 + lane]       * xv;
            ai1 += ls_w[c2 * 512 + lane + 64]  * xv;
            ag0 += ls_w[c2 * 512 + lane + 256] * xv;
            ag1 += ls_w[c2 * 512 + lane + 320] * xv;
            ao0 += ls_w[c2 * 512 + lane + 384] * xv;
            ao1 += ls_w[c2 * 512 + lane + 448] * xv;
        }
        float c0 = sigf(ai0) * tanhf(ag0);
        float c1 = sigf(ai1) * tanhf(ag1);
        float h0 = sigf(ao0) * tanhf(c0);
        float h1 = sigf(ao1) * tanhf(c1);
        if (len == 1) {                    // singleton: done
            hfin[(size_t)idx * HID + lane] = h0;
            hfin[(size_t)idx * HID + lane + 64] = h1;
        } else {                           // multi: park state in LDS
            h_st[s][lane] = h0; h_st[s][lane + 64] = h1;
            c_st[s][lane] = c0; c_st[s][lane + 64] = c1;
        }
    }
    // ---- block-wide recurrence for this block's multi slots ----
    for (int s = 0; s < 8; s++) {
        int len = l_len[s];
        if (len < 2) continue;             // block-uniform branch
        int idx = l_idx[s];
        const int* sl = slots + ((size_t)bb * NRF + chainrf[idx]) * MAXLEN;
        for (int t = 1; t < len; t++) {
            __syncthreads();               // h_st/c_st + prev x_s readers done
            if (tid < 16)
                x_s[tid] = features[((size_t)(bb * N + sl[t])) * C + tid];
            __syncthreads();
            float a0 = ls_b[tid], a1 = ls_b[tid + 256];
#pragma unroll
            for (int c2 = 0; c2 < 16; c2++) {
                float xv = x_s[c2];
                a0 += ls_w[c2 * 512 + tid] * xv;
                a1 += ls_w[c2 * 512 + tid + 256] * xv;
            }
#pragma unroll 8
            for (int k = 0; k < 128; k++) {
                float hv = h_st[s][k];     // LDS broadcast
                a0 += w_hh_T[k * 512 + tid] * hv;
                a1 += w_hh_T[k * 512 + tid + 256] * hv;
            }
            g_s[tid] = a0;
            g_s[tid + 256] = a1;
            __syncthreads();
            if (tid < 128) {
                float ig = sigf(g_s[tid]);
                float fg = sigf(g_s[tid + 128]);
                float gg = tanhf(g_s[tid + 256]);
                float og = sigf(g_s[tid + 384]);
                float cn = fg * c_st[s][tid] + ig * gg;
                c_st[s][tid] = cn;
                h_st[s][tid] = og * tanhf(cn);
            }
        }
        __syncthreads();
        if (tid < 128) hfin[(size_t)idx * HID + tid] = h_st[s][tid];
    }
}

// ---------------- scatter to dense [B, HID, 128, 128] ----------------
__global__ __launch_bounds__(256) void k_scatter(
    const float* __restrict__ hfin, const int* __restrict__ map,
    float* __restrict__ out) {
    int b = blockIdx.x >> 7;        // grid = B*128
    int y = blockIdx.x & 127;
    int t = threadIdx.x;
    int xq = t & 31;                // x quad: covers x = 4*xq .. 4*xq+3
    int hg = t >> 5;                // hid group 0..7 (16 hids each)
    const int4* mrow = (const int4*)(map + b * NRF + y * 128);
    int4 kk = mrow[xq];
    const float* hb = hfin + (size_t)b * MAXCH * HID;
#pragma unroll
    for (int hh = 0; hh < 16; hh++) {
        int hid = hg * 16 + hh;
        float4 v;
        v.x = (kk.x < 0) ? 0.f : hb[kk.x * HID + hid];
        v.y = (kk.y < 0) ? 0.f : hb[kk.y * HID + hid];
        v.z = (kk.z < 0) ? 0.f : hb[kk.z * HID + hid];
        v.w = (kk.w < 0) ? 0.f : hb[kk.w * HID + hid];
        *(float4*)(out + ((((size_t)b * HID + hid) * 128 + y) * 128) + xq * 4) = v;
    }
}

extern "C" void kernel_launch(void* const* d_in, const int* in_sizes, int n_in,
                              void* d_out, int out_size, void* d_ws, size_t ws_size,
                              hipStream_t stream) {
    const float* features = (const float*)d_in[0];   // [B,N,C] f32
    const int*   coords   = (const int*)d_in[1];     // [B,N,2] i32
    const float* w_ih     = (const float*)d_in[2];   // [512,16]
    const float* w_hh     = (const float*)d_in[3];   // [512,128]
    const float* b_ih     = (const float*)d_in[4];   // [512]
    const float* b_hh     = (const float*)d_in[5];   // [512]
    float* out = (float*)d_out;                      // [B,128,128,128]

    char* ws = (char*)d_ws;
    float* w_ih_T   = (float*)(ws + 0);              //    32768 B
    float* w_hh_T   = (float*)(ws + 32768);          //   262144 B
    float* biassum  = (float*)(ws + 294912);         //     2048 B
    int*   map      = (int*)(ws + 296960);           //   524288 B
    int*   cnt      = (int*)(ws + 821248);           //       64 B
    int*   chainrf  = (int*)(ws + 821312);           //    65536 B
    int*   chainlen = (int*)(ws + 886848);           //    65536 B
    int*   slots    = (int*)(ws + 952384);           //  4194304 B
    float* hfin     = (float*)(ws + 5146688);        //  8388608 B -> ~13.5 MB

    k_pre<<<dim3(81), dim3(1024), 0, stream>>>(
        coords, w_ih, w_hh, b_ih, b_hh, w_ih_T, w_hh_T, biassum,
        map, cnt, chainrf, chainlen, slots);
    k_phase<<<dim3(2048), dim3(256), 0, stream>>>(
        features, w_ih_T, w_hh_T, biassum, cnt, chainrf, chainlen, slots, hfin);
    k_scatter<<<dim3(B * 128), dim3(256), 0, stream>>>(hfin, map, out);
}

// Round 10
// 138.284 us; speedup vs baseline: 1.0089x; 1.0089x over previous
//
#include <hip/hip_runtime.h>
#include <hip/hip_bf16.h>
#include <math.h>

#define B 8
#define N 2048
#define C 16
#define HID 128
#define NRF 16384      // 128*128
#define MAXLEN 8
#define MAXCH 2048     // max chains per batch (<= N)

__device__ __forceinline__ float sigf(float x) { return 1.f / (1.f + expf(-x)); }

// ---------------- pre: per-batch build + sort + classify + transpose -------
// Blocks 0..7: one batch each, 1024 threads, counters in LDS (64 KB) -> no
// global init dependency, no cross-block atomics (R0/R1 lesson structural).
// Chain heads time-sort their slots HERE (R9 lesson: phase0's serial tid<8
// sort prologue was dead weight on 2048 blocks). Emits chainpk = ev0|len<<11
// and per-batch multi list (j | rf<<11).
// Blocks 8..80: weight transpose + bias (independent, same dispatch).
__global__ __launch_bounds__(1024) void k_pre(
    const int* __restrict__ coords, const float* __restrict__ w_ih,
    const float* __restrict__ w_hh, const float* __restrict__ b_ih,
    const float* __restrict__ b_hh, float* __restrict__ w_ih_T,
    float* __restrict__ w_hh_T, float* __restrict__ biassum,
    int* __restrict__ map, int* __restrict__ cnt, int* __restrict__ mcnt,
    int* __restrict__ chainpk, int* __restrict__ mlist,
    int* __restrict__ slots) {
    int tid = threadIdx.x;
    if (blockIdx.x < 8) {
        int bb = blockIdx.x;
        __shared__ int cnt_l[NRF];          // 64 KB
        __shared__ int nch_l, nmul_l;
#pragma unroll
        for (int i = 0; i < 16; i++) cnt_l[tid + 1024 * i] = 0;
        if (tid == 0) { nch_l = 0; nmul_l = 0; }
#pragma unroll
        for (int i = 0; i < 16; i++) map[bb * NRF + tid + 1024 * i] = -1;
        __syncthreads();
        int n0 = tid, n1 = tid + 1024;
        int2 c0 = ((const int2*)coords)[bb * N + n0];
        int2 c1 = ((const int2*)coords)[bb * N + n1];
        int rf0 = c0.y * 128 + c0.x;
        int rf1 = c1.y * 128 + c1.x;
        int pos0 = atomicAdd(&cnt_l[rf0], 1);
        int pos1 = atomicAdd(&cnt_l[rf1], 1);
        if (pos0 < MAXLEN) slots[((size_t)bb * NRF + rf0) * MAXLEN + pos0] = n0;
        if (pos1 < MAXLEN) slots[((size_t)bb * NRF + rf1) * MAXLEN + pos1] = n1;
        __syncthreads();                    // counts + slot stores visible
#pragma unroll
        for (int e = 0; e < 2; e++) {
            int rf = e ? rf1 : rf0;
            int pos = e ? pos1 : pos0;
            if (pos == 0) {                 // chain head
                int j = atomicAdd(&nch_l, 1);            // LDS atomic
                int len = cnt_l[rf];
                if (len > MAXLEN) len = MAXLEN;
                map[bb * NRF + rf] = j;
                int* sl = slots + ((size_t)bb * NRF + rf) * MAXLEN;
                int ev[MAXLEN];
#pragma unroll
                for (int t = 0; t < MAXLEN; t++) {
                    int v = sl[t];
                    ev[t] = (t < len) ? v : 0x7fffffff;
                }
#pragma unroll
                for (int a = 0; a < MAXLEN; a++)   // time-sort
#pragma unroll
                    for (int q = 0; q < MAXLEN - 1; q++) {
                        int u = ev[q], v = ev[q + 1];
                        ev[q] = min(u, v);
                        ev[q + 1] = max(u, v);
                    }
                if (len >= 2) {
                    for (int t = 0; t < len; t++) sl[t] = ev[t];
                    int m = atomicAdd(&nmul_l, 1);
                    if (m < 1024) mlist[bb * 1024 + m] = j | (rf << 11);
                }
                chainpk[bb * MAXCH + j] = ev[0] | (len << 11);
            }
        }
        __syncthreads();
        if (tid == 0) {
            cnt[bb] = nch_l;
            mcnt[bb] = (nmul_l > 1024) ? 1024 : nmul_l;
        }
    } else {
        int i = (blockIdx.x - 8) * 1024 + tid;   // 73 blocks cover 74240
        if (i < C * 512) {                 // w_ih_T[c][j] = w_ih[j][c]
            int c = i >> 9, j = i & 511;
            w_ih_T[i] = w_ih[j * C + c];
        }
        if (i < HID * 512) {               // w_hh_T[k][j] = w_hh[j][k]
            int k = i >> 9, j = i & 511;
            w_hh_T[i] = w_hh[j * HID + k];
        }
        if (i < 512) biassum[i] = b_ih[i] + b_hh[i];
    }
}

// ---------------- gate0: step-0 for EVERY chain (c_prev=0, f-gate dead) ----
// 1024 blocks x 256 = exactly one residency round at 4 blocks/CU (34.5 KB
// LDS). 16 slots/block, 4 chains/wave; all 4 feature loads issued before
// compute (latency batched). Weights from LDS: 2 lanes/bank = free (G4).
__global__ __launch_bounds__(256) void k_gate0(
    const float* __restrict__ features, const float* __restrict__ w_ih_T,
    const float* __restrict__ biassum, const int* __restrict__ cnt,
    const int* __restrict__ chainpk, float* __restrict__ hfin,
    float* __restrict__ cfin) {
    int tid = threadIdx.x;
    int bb = blockIdx.x >> 7;              // 128 blocks per batch
    int slot0 = (blockIdx.x & 127) * 16;
    __shared__ float ls_w[C * 512];        // 32 KB
    __shared__ float ls_b[512];
    __shared__ int l_pk[16];
    int nc = cnt[bb];
    if (tid < 16) {
        int j = slot0 + tid;
        l_pk[tid] = (j < nc) ? chainpk[bb * MAXCH + j] : -1;   // coalesced
    }
    for (int i = tid; i < C * 128; i += 256)        // float4 staging
        ((float4*)ls_w)[i] = ((const float4*)w_ih_T)[i];
    ls_b[tid] = biassum[tid];
    ls_b[tid + 256] = biassum[tid + 256];
    __syncthreads();
    int w = tid >> 6, lane = tid & 63;
    int pk[4];
    float f[4];
#pragma unroll
    for (int s2 = 0; s2 < 4; s2++) {       // issue ALL feature loads first
        pk[s2] = l_pk[w * 4 + s2];
        f[s2] = 0.f;
        if (pk[s2] >= 0 && lane < 16)
            f[s2] = features[((size_t)(bb * N + (pk[s2] & 2047))) * C + lane];
    }
#pragma unroll
    for (int s2 = 0; s2 < 4; s2++) {
        if (pk[s2] < 0) continue;
        int len = pk[s2] >> 11;
        float ai0 = ls_b[lane],       ai1 = ls_b[lane + 64];
        float ag0 = ls_b[lane + 256], ag1 = ls_b[lane + 320];
        float ao0 = ls_b[lane + 384], ao1 = ls_b[lane + 448];
#pragma unroll
        for (int c2 = 0; c2 < 16; c2++) {
            float xv = __shfl(f[s2], c2, 64);
            ai0 += ls_w[c2 * 512 + lane]       * xv;
            ai1 += ls_w[c2 * 512 + lane + 64]  * xv;
            ag0 += ls_w[c2 * 512 + lane + 256] * xv;
            ag1 += ls_w[c2 * 512 + lane + 320] * xv;
            ao0 += ls_w[c2 * 512 + lane + 384] * xv;
            ao1 += ls_w[c2 * 512 + lane + 448] * xv;
        }
        float c0 = sigf(ai0) * tanhf(ag0);
        float c1 = sigf(ai1) * tanhf(ag1);
        float h0 = sigf(ao0) * tanhf(c0);
        float h1 = sigf(ao1) * tanhf(c1);
        size_t idx = (size_t)(bb * MAXCH + slot0 + w * 4 + s2);
        hfin[idx * HID + lane] = h0;
        hfin[idx * HID + lane + 64] = h1;
        if (len >= 2) {
            cfin[idx * HID + lane] = c0;
            cfin[idx * HID + lane + 64] = c1;
        }
    }
}

// ---------------- recur: ONE block per multi chain (R9 lesson: never
// serialize chains within a block). ~940 concurrent 256-thread blocks;
// thread = 2 gate cols; per step 288 pipelined L2 loads; h/c/x in LDS.
__global__ __launch_bounds__(256) void k_recur(
    const float* __restrict__ features, const float* __restrict__ w_ih_T,
    const float* __restrict__ w_hh_T, const float* __restrict__ biassum,
    const int* __restrict__ chainpk, const int* __restrict__ mcnt,
    const int* __restrict__ mlist, const int* __restrict__ slots,
    float* __restrict__ hfin, const float* __restrict__ cfin) {
    int tid = threadIdx.x;
    int bb = blockIdx.x >> 7;           // 8 batches x 128 slots
    int m0 = blockIdx.x & 127;
    int M = mcnt[bb];
    if (m0 >= M) return;
    __shared__ float h_s[HID], c_s[HID];
    __shared__ float x_s[16];
    __shared__ float g_s[512];
    float bs0 = biassum[tid], bs1 = biassum[tid + 256];
    for (int m = m0; m < M; m += 128) { // typically exactly 1 iteration
        int e = mlist[bb * 1024 + m];
        int j = e & 2047;
        int rf = e >> 11;
        size_t idx = (size_t)(bb * MAXCH + j);
        int len = chainpk[bb * MAXCH + j] >> 11;
        const int* sl = slots + ((size_t)bb * NRF + rf) * MAXLEN;  // sorted
        if (tid < 16) x_s[tid] = features[((size_t)(bb * N + sl[1])) * C + tid];
        if (tid < 128) {
            h_s[tid] = hfin[idx * HID + tid];
            c_s[tid] = cfin[idx * HID + tid];
        }
        __syncthreads();
        for (int t = 1; t < len; t++) {    // len block-uniform
            float a0 = bs0, a1 = bs1, b0 = 0.f, b1 = 0.f;
#pragma unroll
            for (int c2 = 0; c2 < 16; c2++) {
                float xv = x_s[c2];
                a0 += w_ih_T[c2 * 512 + tid] * xv;
                a1 += w_ih_T[c2 * 512 + tid + 256] * xv;
            }
#pragma unroll 8
            for (int k = 0; k < 128; k += 2) {
                float h0 = h_s[k], h1 = h_s[k + 1];
                a0 += w_hh_T[k * 512 + tid] * h0;
                a1 += w_hh_T[k * 512 + tid + 256] * h0;
                b0 += w_hh_T[(k + 1) * 512 + tid] * h1;
                b1 += w_hh_T[(k + 1) * 512 + tid + 256] * h1;
            }
            g_s[tid] = a0 + b0;
            g_s[tid + 256] = a1 + b1;
            __syncthreads();               // gates ready; x_s readers done
            if (tid < 128) {
                float ig = sigf(g_s[tid]);
                float fg = sigf(g_s[tid + 128]);
                float gg = tanhf(g_s[tid + 256]);
                float og = sigf(g_s[tid + 384]);
                float cn = fg * c_s[tid] + ig * gg;
                c_s[tid] = cn;
                h_s[tid] = og * tanhf(cn);
            }
            if (tid < 16 && t + 1 < len)   // prefetch next x
                x_s[tid] = features[((size_t)(bb * N + sl[t + 1])) * C + tid];
            __syncthreads();
        }
        if (tid < 128) hfin[idx * HID + tid] = h_s[tid];
        __syncthreads();                   // before LDS reuse by next m
    }
}

// ---------------- scatter to dense [B, HID, 128, 128] ----------------
__global__ __launch_bounds__(256) void k_scatter(
    const float* __restrict__ hfin, const int* __restrict__ map,
    float* __restrict__ out) {
    int b = blockIdx.x >> 7;        // grid = B*128
    int y = blockIdx.x & 127;
    int t = threadIdx.x;
    int xq = t & 31;                // x quad: covers x = 4*xq .. 4*xq+3
    int hg = t >> 5;                // hid group 0..7 (16 hids each)
    const int4* mrow = (const int4*)(map + b * NRF + y * 128);
    int4 kk = mrow[xq];
    const float* hb = hfin + (size_t)b * MAXCH * HID;
#pragma unroll
    for (int hh = 0; hh < 16; hh++) {
        int hid = hg * 16 + hh;
        float4 v;
        v.x = (kk.x < 0) ? 0.f : hb[kk.x * HID + hid];
        v.y = (kk.y < 0) ? 0.f : hb[kk.y * HID + hid];
        v.z = (kk.z < 0) ? 0.f : hb[kk.z * HID + hid];
        v.w = (kk.w < 0) ? 0.f : hb[kk.w * HID + hid];
        *(float4*)(out + ((((size_t)b * HID + hid) * 128 + y) * 128) + xq * 4) = v;
    }
}

extern "C" void kernel_launch(void* const* d_in, const int* in_sizes, int n_in,
                              void* d_out, int out_size, void* d_ws, size_t ws_size,
                              hipStream_t stream) {
    const float* features = (const float*)d_in[0];   // [B,N,C] f32
    const int*   coords   = (const int*)d_in[1];     // [B,N,2] i32
    const float* w_ih     = (const float*)d_in[2];   // [512,16]
    const float* w_hh     = (const float*)d_in[3];   // [512,128]
    const float* b_ih     = (const float*)d_in[4];   // [512]
    const float* b_hh     = (const float*)d_in[5];   // [512]
    float* out = (float*)d_out;                      // [B,128,128,128]

    char* ws = (char*)d_ws;
    float* w_ih_T   = (float*)(ws + 0);              //    32768 B
    float* w_hh_T   = (float*)(ws + 32768);          //   262144 B
    float* biassum  = (float*)(ws + 294912);         //     2048 B
    int*   map      = (int*)(ws + 296960);           //   524288 B
    int*   cnt      = (int*)(ws + 821248);           //       64 B
    int*   mcnt     = (int*)(ws + 821312);           //       64 B
    int*   chainpk  = (int*)(ws + 821376);           //    65536 B
    int*   mlist    = (int*)(ws + 886912);           //    32768 B
    int*   slots    = (int*)(ws + 919680);           //  4194304 B
    float* hfin     = (float*)(ws + 5113984);        //  8388608 B
    float* cfin     = (float*)(ws + 13502592);       //  8388608 B -> ~21.9 MB

    k_pre<<<dim3(81), dim3(1024), 0, stream>>>(
        coords, w_ih, w_hh, b_ih, b_hh, w_ih_T, w_hh_T, biassum,
        map, cnt, mcnt, chainpk, mlist, slots);
    k_gate0<<<dim3(1024), dim3(256), 0, stream>>>(
        features, w_ih_T, biassum, cnt, chainpk, hfin, cfin);
    k_recur<<<dim3(1024), dim3(256), 0, stream>>>(
        features, w_ih_T, w_hh_T, biassum, chainpk, mcnt, mlist, slots,
        hfin, cfin);
    k_scatter<<<dim3(B * 128), dim3(256), 0, stream>>>(hfin, map, out);
}

// Round 11
// 128.456 us; speedup vs baseline: 1.0860x; 1.0765x over previous
//
#include <hip/hip_runtime.h>
#include <hip/hip_bf16.h>
#include <math.h>

#define B 8
#define N 2048
#define C 16
#define HID 128
#define NRF 16384      // 128*128
#define MAXLEN 8
#define MAXCH 2048     // max chains per batch (<= N)

__device__ __forceinline__ float sigf(float x) { return 1.f / (1.f + expf(-x)); }

// ---------------- pre: per-batch build + sort + classify + transpose -------
// Blocks 0..7: one batch each, 1024 threads, counters in LDS (64 KB) -> no
// global init dependency, no cross-block atomics (R0/R1 lesson structural).
// Chain heads time-sort their slots here; emits chainpk = ev0|len<<11 and a
// per-batch multi list (j | rf<<11).
// Blocks 8..80: weight transpose + bias (independent, same dispatch).
__global__ __launch_bounds__(1024) void k_pre(
    const int* __restrict__ coords, const float* __restrict__ w_ih,
    const float* __restrict__ w_hh, const float* __restrict__ b_ih,
    const float* __restrict__ b_hh, float* __restrict__ w_ih_T,
    float* __restrict__ w_hh_T, float* __restrict__ biassum,
    int* __restrict__ map, int* __restrict__ cnt, int* __restrict__ mcnt,
    int* __restrict__ chainpk, int* __restrict__ mlist,
    int* __restrict__ slots) {
    int tid = threadIdx.x;
    if (blockIdx.x < 8) {
        int bb = blockIdx.x;
        __shared__ int cnt_l[NRF];          // 64 KB
        __shared__ int nch_l, nmul_l;
#pragma unroll
        for (int i = 0; i < 16; i++) cnt_l[tid + 1024 * i] = 0;
        if (tid == 0) { nch_l = 0; nmul_l = 0; }
#pragma unroll
        for (int i = 0; i < 16; i++) map[bb * NRF + tid + 1024 * i] = -1;
        __syncthreads();
        int n0 = tid, n1 = tid + 1024;
        int2 c0 = ((const int2*)coords)[bb * N + n0];
        int2 c1 = ((const int2*)coords)[bb * N + n1];
        int rf0 = c0.y * 128 + c0.x;
        int rf1 = c1.y * 128 + c1.x;
        int pos0 = atomicAdd(&cnt_l[rf0], 1);
        int pos1 = atomicAdd(&cnt_l[rf1], 1);
        if (pos0 < MAXLEN) slots[((size_t)bb * NRF + rf0) * MAXLEN + pos0] = n0;
        if (pos1 < MAXLEN) slots[((size_t)bb * NRF + rf1) * MAXLEN + pos1] = n1;
        __syncthreads();                    // counts + slot stores visible
#pragma unroll
        for (int e = 0; e < 2; e++) {
            int rf = e ? rf1 : rf0;
            int pos = e ? pos1 : pos0;
            if (pos == 0) {                 // chain head
                int j = atomicAdd(&nch_l, 1);            // LDS atomic
                int len = cnt_l[rf];
                if (len > MAXLEN) len = MAXLEN;
                map[bb * NRF + rf] = j;
                int* sl = slots + ((size_t)bb * NRF + rf) * MAXLEN;
                int ev[MAXLEN];
#pragma unroll
                for (int t = 0; t < MAXLEN; t++) {
                    int v = sl[t];
                    ev[t] = (t < len) ? v : 0x7fffffff;
                }
#pragma unroll
                for (int a = 0; a < MAXLEN; a++)   // time-sort
#pragma unroll
                    for (int q = 0; q < MAXLEN - 1; q++) {
                        int u = ev[q], v = ev[q + 1];
                        ev[q] = min(u, v);
                        ev[q + 1] = max(u, v);
                    }
                if (len >= 2) {
                    for (int t = 0; t < len; t++) sl[t] = ev[t];
                    int m = atomicAdd(&nmul_l, 1);
                    if (m < 1024) mlist[bb * 1024 + m] = j | (rf << 11);
                }
                chainpk[bb * MAXCH + j] = ev[0] | (len << 11);
            }
        }
        __syncthreads();
        if (tid == 0) {
            cnt[bb] = nch_l;
            mcnt[bb] = (nmul_l > 1024) ? 1024 : nmul_l;
        }
    } else {
        int i = (blockIdx.x - 8) * 1024 + tid;   // 73 blocks cover 74240
        if (i < C * 512) {                 // w_ih_T[c][j] = w_ih[j][c]
            int c = i >> 9, j = i & 511;
            w_ih_T[i] = w_ih[j * C + c];
        }
        if (i < HID * 512) {               // w_hh_T[k][j] = w_hh[j][k]
            int k = i >> 9, j = i & 511;
            w_hh_T[i] = w_hh[j * HID + k];
        }
        if (i < 512) biassum[i] = b_ih[i] + b_hh[i];
    }
}

// ---------------- main: fused, DISJOINT block roles (no cross-block dep) ---
// Blocks 0..1023: recur — one block per multi chain, computes its OWN step-0
//   (trivial matvec) so it never reads gate0 output; c state lives in LDS
//   only (cfin deleted). Placed FIRST in the grid so the longest chains (the
//   critical path) start immediately.
// Blocks 1024..2047: gate0 — 16 slots/block, SINGLETONS only (multi chains
//   wholly owned by recur -> no hfin write race). Fills CUs around recur.
// R8 lesson (no serial multi chains per block) + R10 lesson (dispatch gaps
// and cfin round-trip cost more than fusion saves) combined.
__global__ __launch_bounds__(512) void k_main(
    const float* __restrict__ features, const float* __restrict__ w_ih_T,
    const float* __restrict__ w_hh_T, const float* __restrict__ biassum,
    const int* __restrict__ cnt, const int* __restrict__ chainpk,
    const int* __restrict__ mcnt, const int* __restrict__ mlist,
    const int* __restrict__ slots, float* __restrict__ hfin) {
    int tid = threadIdx.x;
    __shared__ float ls_w[C * 512];        // gate0: 32 KB
    __shared__ float ls_b[512];
    __shared__ int l_pk[16];
    __shared__ float h_s[HID], c_s[HID], x_s[16], g_s[512];   // recur: ~3 KB

    if (blockIdx.x < 1024) {
        // ---------------- recur part: one block per multi chain ------------
        int bb = blockIdx.x >> 7;          // 8 batches x 128 slots
        int m0 = blockIdx.x & 127;
        int M = mcnt[bb];
        if (m0 >= M) return;
        float wi[16];
#pragma unroll
        for (int c2 = 0; c2 < 16; c2++) wi[c2] = w_ih_T[c2 * 512 + tid];
        float bs = biassum[tid];
        for (int m = m0; m < M; m += 128) {   // typically exactly 1 iter
            int e = mlist[bb * 1024 + m];
            int j = e & 2047, rf = e >> 11;
            size_t idx = (size_t)(bb * MAXCH + j);
            int len = chainpk[bb * MAXCH + j] >> 11;
            const int* sl = slots + ((size_t)bb * NRF + rf) * MAXLEN;  // sorted
            if (tid < 16) x_s[tid] = features[((size_t)(bb * N + sl[0])) * C + tid];
            if (tid < 128) c_s[tid] = 0.f;
            __syncthreads();
            for (int t = 0; t < len; t++) {   // len block-uniform
                float a0 = bs, a1 = 0.f, a2 = 0.f, a3 = 0.f;
#pragma unroll
                for (int c2 = 0; c2 < 16; c2++) a0 += wi[c2] * x_s[c2];
                if (t > 0) {
#pragma unroll 8
                    for (int k = 0; k < 128; k += 4) {
                        a0 += w_hh_T[k * 512 + tid]       * h_s[k];
                        a1 += w_hh_T[(k + 1) * 512 + tid] * h_s[k + 1];
                        a2 += w_hh_T[(k + 2) * 512 + tid] * h_s[k + 2];
                        a3 += w_hh_T[(k + 3) * 512 + tid] * h_s[k + 3];
                    }
                }
                g_s[tid] = (a0 + a1) + (a2 + a3);
                __syncthreads();              // gates ready; x_s readers done
                if (tid < 128) {
                    float ig = sigf(g_s[tid]);
                    float fg = sigf(g_s[tid + 128]);
                    float gg = tanhf(g_s[tid + 256]);
                    float og = sigf(g_s[tid + 384]);
                    float cn = fg * c_s[tid] + ig * gg;   // t=0: c=0
                    c_s[tid] = cn;
                    h_s[tid] = og * tanhf(cn);
                }
                if (tid < 16 && t + 1 < len)  // prefetch next x
                    x_s[tid] = features[((size_t)(bb * N + sl[t + 1])) * C + tid];
                __syncthreads();
            }
            if (tid < 128) hfin[idx * HID + tid] = h_s[tid];
            __syncthreads();                  // before LDS reuse by next m
        }
    } else {
        // ---------------- gate0 part: singletons only ----------------------
        int b2 = blockIdx.x - 1024;
        int bb = b2 >> 7;                  // 128 blocks per batch
        int slot0 = (b2 & 127) * 16;
        int nc = cnt[bb];
        if (tid < 16) {
            int j = slot0 + tid;
            l_pk[tid] = (j < nc) ? chainpk[bb * MAXCH + j] : -1;
        }
        for (int i = tid; i < C * 128; i += 512)       // float4 staging
            ((float4*)ls_w)[i] = ((const float4*)w_ih_T)[i];
        ls_b[tid] = biassum[tid];
        __syncthreads();
        int w = tid >> 6, lane = tid & 63;
        int pk[2];
        float f[2];
#pragma unroll
        for (int s2 = 0; s2 < 2; s2++) {   // issue all feature loads first
            pk[s2] = l_pk[w * 2 + s2];
            f[s2] = 0.f;
            if (pk[s2] >= 0 && (pk[s2] >> 11) == 1 && lane < 16)
                f[s2] = features[((size_t)(bb * N + (pk[s2] & 2047))) * C + lane];
        }
#pragma unroll
        for (int s2 = 0; s2 < 2; s2++) {
            if (pk[s2] < 0 || (pk[s2] >> 11) != 1) continue;  // multi: recur owns
            float ai0 = ls_b[lane],       ai1 = ls_b[lane + 64];
            float ag0 = ls_b[lane + 256], ag1 = ls_b[lane + 320];
            float ao0 = ls_b[lane + 384], ao1 = ls_b[lane + 448];
#pragma unroll
            for (int c2 = 0; c2 < 16; c2++) {
                float xv = __shfl(f[s2], c2, 64);
                ai0 += ls_w[c2 * 512 + lane]       * xv;
                ai1 += ls_w[c2 * 512 + lane + 64]  * xv;
                ag0 += ls_w[c2 * 512 + lane + 256] * xv;
                ag1 += ls_w[c2 * 512 + lane + 320] * xv;
                ao0 += ls_w[c2 * 512 + lane + 384] * xv;
                ao1 += ls_w[c2 * 512 + lane + 448] * xv;
            }
            float c0 = sigf(ai0) * tanhf(ag0);     // c_prev=0 -> f-gate dead
            float c1 = sigf(ai1) * tanhf(ag1);
            float h0 = sigf(ao0) * tanhf(c0);
            float h1 = sigf(ao1) * tanhf(c1);
            size_t idx = (size_t)(bb * MAXCH + slot0 + w * 2 + s2);
            hfin[idx * HID + lane] = h0;
            hfin[idx * HID + lane + 64] = h1;
        }
    }
}

// ---------------- scatter to dense [B, HID, 128, 128] ----------------
__global__ __launch_bounds__(256) void k_scatter(
    const float* __restrict__ hfin, const int* __restrict__ map,
    float* __restrict__ out) {
    int b = blockIdx.x >> 7;        // grid = B*128
    int y = blockIdx.x & 127;
    int t = threadIdx.x;
    int xq = t & 31;                // x quad: covers x = 4*xq .. 4*xq+3
    int hg = t >> 5;                // hid group 0..7 (16 hids each)
    const int4* mrow = (const int4*)(map + b * NRF + y * 128);
    int4 kk = mrow[xq];
    const float* hb = hfin + (size_t)b * MAXCH * HID;
#pragma unroll
    for (int hh = 0; hh < 16; hh++) {
        int hid = hg * 16 + hh;
        float4 v;
        v.x = (kk.x < 0) ? 0.f : hb[kk.x * HID + hid];
        v.y = (kk.y < 0) ? 0.f : hb[kk.y * HID + hid];
        v.z = (kk.z < 0) ? 0.f : hb[kk.z * HID + hid];
        v.w = (kk.w < 0) ? 0.f : hb[kk.w * HID + hid];
        *(float4*)(out + ((((size_t)b * HID + hid) * 128 + y) * 128) + xq * 4) = v;
    }
}

extern "C" void kernel_launch(void* const* d_in, const int* in_sizes, int n_in,
                              void* d_out, int out_size, void* d_ws, size_t ws_size,
                              hipStream_t stream) {
    const float* features = (const float*)d_in[0];   // [B,N,C] f32
    const int*   coords   = (const int*)d_in[1];     // [B,N,2] i32
    const float* w_ih     = (const float*)d_in[2];   // [512,16]
    const float* w_hh     = (const float*)d_in[3];   // [512,128]
    const float* b_ih     = (const float*)d_in[4];   // [512]
    const float* b_hh     = (const float*)d_in[5];   // [512]
    float* out = (float*)d_out;                      // [B,128,128,128]

    char* ws = (char*)d_ws;
    float* w_ih_T   = (float*)(ws + 0);              //    32768 B
    float* w_hh_T   = (float*)(ws + 32768);          //   262144 B
    float* biassum  = (float*)(ws + 294912);         //     2048 B
    int*   map      = (int*)(ws + 296960);           //   524288 B
    int*   cnt      = (int*)(ws + 821248);           //       64 B
    int*   mcnt     = (int*)(ws + 821312);           //       64 B
    int*   chainpk  = (int*)(ws + 821376);           //    65536 B
    int*   mlist    = (int*)(ws + 886912);           //    32768 B
    int*   slots    = (int*)(ws + 919680);           //  4194304 B
    float* hfin     = (float*)(ws + 5113984);        //  8388608 B -> ~13.5 MB

    k_pre<<<dim3(81), dim3(1024), 0, stream>>>(
        coords, w_ih, w_hh, b_ih, b_hh, w_ih_T, w_hh_T, biassum,
        map, cnt, mcnt, chainpk, mlist, slots);
    k_main<<<dim3(2048), dim3(512), 0, stream>>>(
        features, w_ih_T, w_hh_T, biassum, cnt, chainpk, mcnt, mlist,
        slots, hfin);
    k_scatter<<<dim3(B * 128), dim3(256), 0, stream>>>(hfin, map, out);
}